// Round 10
// baseline (209.047 us; speedup 1.0000x reference)
//
#include <hip/hip_runtime.h>
#include <hip/hip_bf16.h>
#include <stdint.h>

// Problem constants (all inputs & output are FP32 per the reference file)
#define BATCH 128
#define LAT   2000
#define NG    10000
#define KW    20
#define OUTW  (NG * KW)   // 200000
#define EPSV  1e-5f

#define NKT   32            // 64-wide k-tiles in padded z/W (2048 = 32*64)
#define EG    80            // groups per block (NG = 125 * 80; 80 = 5 m-tiles)
#define HR_STRIDE 132       // h LDS row stride (floats): <=2-way bank alias

typedef __bf16 bf16x8 __attribute__((ext_vector_type(8)));
typedef float  f32x4  __attribute__((ext_vector_type(4)));

__device__ __forceinline__ ushort f2bf(float f) {
  uint32_t u = __builtin_bit_cast(uint32_t, f);
  u = (u + 0x7FFFu + ((u >> 16) & 1u)) >> 16;  // RNE
  return (ushort)u;
}

__device__ __forceinline__ int4 pack8(const float* p) {
  float4 f0 = *(const float4*)p;
  float4 f1 = *(const float4*)(p + 4);
  int4 v;
  v.x = (int)((uint32_t)f2bf(f0.x) | ((uint32_t)f2bf(f0.y) << 16));
  v.y = (int)((uint32_t)f2bf(f0.z) | ((uint32_t)f2bf(f0.w) << 16));
  v.z = (int)((uint32_t)f2bf(f1.x) | ((uint32_t)f2bf(f1.y) << 16));
  v.w = (int)((uint32_t)f2bf(f1.z) | ((uint32_t)f2bf(f1.w) << 16));
  return v;
}

// native packed RNE f32->bf16 (compiler emits v_cvt_pk_bf16_f32 pairs)
__device__ __forceinline__ bf16x8 cvt8(float4 a, float4 b) {
  bf16x8 r;
  r[0] = (__bf16)a.x; r[1] = (__bf16)a.y; r[2] = (__bf16)a.z; r[3] = (__bf16)a.w;
  r[4] = (__bf16)b.x; r[5] = (__bf16)b.y; r[6] = (__bf16)b.z; r[7] = (__bf16)b.w;
  return r;
}

// =====================================================================
// Phase 0: z (128 x 2000 f32) -> bf16 image permuted to WAVE-COALESCED
// fragment order: chunk ((kt*2+kk)*8 + bgrp)*64 + q*16 + cl holds
// z[bgrp*16+cl][kt*64 + kk*32 + q*8 .. +8]. A wave's 64 lanes read 64
// CONSECUTIVE chunks -> 1 KB coalesced. Zero-padded above k=2000.
// =====================================================================
__global__ __launch_bounds__(256) void zprep_kernel(
    const float* __restrict__ zp, int4* __restrict__ zlin) {
  const int cg = blockIdx.x * 256 + threadIdx.x;   // 0..32767
  const int r  = cg >> 8;        // batch row 0..127
  const int ck = cg & 255;       // 16B chunk in row; k0 = ck*8
  const int k0 = ck * 8;
  int4 v = make_int4(0, 0, 0, 0);
  if (k0 < LAT) v = pack8(zp + (size_t)r * LAT + k0);  // LAT%8==0: no straddle
  const int kt = ck >> 3, kk = (ck >> 2) & 1, q = ck & 3;
  const int dst = ((kt * 2 + kk) * 8 + (r >> 4)) * 64 + q * 16 + (r & 15);
  zlin[dst] = v;
}

// =====================================================================
// Fused pipeline, TRAFFIC-MINIMIZED: EG=80 groups/block -> z re-read drops
// from 320 MB (EG=16) to 64 MB chip-wide; total cross-L2 traffic ~244 MB
// (W 80 + z 64 + out 100), the quantity that measured 6.8 TB/s and bound
// all prior variants at ~73 us.
// 125 blocks x 1024 threads = 16 waves: wave w = (batch-group w&7) x
// (k-half w>>3). Wave computes 5 m-tiles (80 groups) x 16 batches x 16
// k-tiles; k-halves combine in h_raw (r8-proven).
// W staged per k-tile into LDS (two tiles/iter, one per k-half),
// register-double-buffered: loads for it+1 issue before compute(it),
// cvt(native pk)+ds_write after, ONE barrier/iter. A-frags: ds_read_b128
// from XOR-swizzled tile. B-frags: direct from permuted z image (1 KB
// coalesced wave-loads, depth-2 register pipeline).
// Then: h combine -> BN stats (wave x 5 groups) -> coalesced expand.
// =====================================================================
__global__ __launch_bounds__(1024, 4) void fused80_kernel(
    const int4* __restrict__ zlin, const float* __restrict__ wp,
    const float* __restrict__ gammap, const float* __restrict__ betap,
    const float* __restrict__ convwp, const float* __restrict__ convbp,
    float* __restrict__ out) {
  const int tid = threadIdx.x;
  const int g0  = blockIdx.x * EG;

  // Wt: [buf][khalf][80 rows x 64 bf16, XOR-swizzled 16B chunks] = 40 KB
  __shared__ __attribute__((aligned(16))) ushort Wt[4 * 5120];
  __shared__ float  h_raw[EG * HR_STRIDE];   // 42.2 KB
  __shared__ float4 cw_s[EG * 5];            // 6.4 KB
  __shared__ float  cb_s[EG];
  __shared__ float  scale_s[EG];
  __shared__ float  shift_s[EG];

  if (tid < EG * 5)
    cw_s[tid] = *(const float4*)(convwp + (size_t)g0 * KW + tid * 4);
  if (tid < EG) cb_s[tid] = convbp[g0 + tid];

  const int lane = tid & 63;
  const int w    = tid >> 6;       // wave id 0..15
  const int wg   = w & 7;          // batch-group 0..7
  const int half = w >> 3;         // k-half: tiles half*16 .. +15
  const int q    = lane >> 4;      // 0..3
  const int cl   = lane & 15;      // 0..15
  const int rb   = wg * 16 + cl;   // batch row (B operand)
  const int t0   = half * 16;

  const int4* zw = zlin + (size_t)wg * 64 + lane;

  // ---- staging chunk descriptors (1280 chunks = 2 tiles x 640) ----
  // chunk0 = tid (0..1023); chunk1 = 1024+tid for tid<256.
  const int c0h  = (tid >= 640);                 // k-half of chunk0
  const int c0r  = (tid - c0h * 640) >> 3;       // row 0..79
  const int c0j  = tid & 7;
  const float* c0p = wp + (size_t)(g0 + c0r) * LAT;
  const int c0kb = c0h * 1024 + c0j * 8;         // + it*64 at runtime
  const int inner0 = c0h * 5120 + c0r * 64 + ((c0j ^ (c0r & 7)) << 3);
  const int c1r  = (384 + tid) >> 3;             // rows 48..79 (k-half 1)
  const int c1j  = tid & 7;                      // (1024+tid)&7 == tid&7
  const float* c1p = wp + (size_t)(g0 + c1r) * LAT;
  const int c1kb = 1024 + c1j * 8;
  const int inner1 = 5120 + c1r * 64 + ((c1j ^ (c1r & 7)) << 3);

  // ---- A-frag read offsets (within a buf): mt stride 1024 ----
  const int a0off = half * 5120 + cl * 64 + ((q       ^ (cl & 7)) << 3);
  const int a1off = half * 5120 + cl * 64 + (((4 + q) ^ (cl & 7)) << 3);

  f32x4 acc[5];
  const f32x4 vzero = {0.f, 0.f, 0.f, 0.f};
#pragma unroll
  for (int i = 0; i < 5; ++i) acc[i] = vzero;
  const float4 fz4 = make_float4(0.f, 0.f, 0.f, 0.f);

  // ---- prologue: stage tile-set 0 -> buf0; z tiles t0,t0+1 in flight ----
  float4 P0 = fz4, P1 = fz4, P2 = fz4, P3 = fz4;
  {
    int k0 = c0kb;
    if (k0 < LAT) { P0 = *(const float4*)(c0p + k0);
                    P1 = *(const float4*)(c0p + k0 + 4); }
    if (tid < 256) {
      int k1 = c1kb;
      if (k1 < LAT) { P2 = *(const float4*)(c1p + k1);
                      P3 = *(const float4*)(c1p + k1 + 4); }
    }
  }
  int4 za0 = zw[(size_t)(t0 * 2 + 0) * 512], za1 = zw[(size_t)(t0 * 2 + 1) * 512];
  int4 zb0 = zw[(size_t)(t0 * 2 + 2) * 512], zb1 = zw[(size_t)(t0 * 2 + 3) * 512];
  *(bf16x8*)&Wt[inner0] = cvt8(P0, P1);
  if (tid < 256) *(bf16x8*)&Wt[inner1] = cvt8(P2, P3);
  __syncthreads();

  // ---- k-loop: 16 iters, reg-dbuf staging, ONE barrier/iter ----
#pragma unroll 2
  for (int it = 0; it < 16; ++it) {
    const int cbuf = it & 1, nbuf = cbuf ^ 1;

    // issue W loads for it+1 (hidden under compute)
    float4 Q0 = fz4, Q1 = fz4, Q2 = fz4, Q3 = fz4;
    if (it < 15) {
      int k0 = c0kb + (it + 1) * 64;
      if (k0 < LAT) { Q0 = *(const float4*)(c0p + k0);
                      Q1 = *(const float4*)(c0p + k0 + 4); }
      if (tid < 256) {
        int k1 = c1kb + (it + 1) * 64;
        if (k1 < LAT) { Q2 = *(const float4*)(c1p + k1);
                        Q3 = *(const float4*)(c1p + k1 + 4); }
      }
    }
    // z prefetch (depth 2); tail: dead reload
    const int i2 = (it + 2 < 16) ? (it + 2) : it;
    int4 nz0 = zw[(size_t)((t0 + i2) * 2 + 0) * 512];
    int4 nz1 = zw[(size_t)((t0 + i2) * 2 + 1) * 512];

    // compute tile t0+it: 10 ds_read + 10 MFMA
    {
      const ushort* wb = &Wt[cbuf * 10240];
#pragma unroll
      for (int mt = 0; mt < 5; ++mt) {
        bf16x8 a = *(const bf16x8*)&wb[a0off + mt * 1024];
        acc[mt] = __builtin_amdgcn_mfma_f32_16x16x32_bf16(
            a, __builtin_bit_cast(bf16x8, za0), acc[mt], 0, 0, 0);
      }
#pragma unroll
      for (int mt = 0; mt < 5; ++mt) {
        bf16x8 a = *(const bf16x8*)&wb[a1off + mt * 1024];
        acc[mt] = __builtin_amdgcn_mfma_f32_16x16x32_bf16(
            a, __builtin_bit_cast(bf16x8, za1), acc[mt], 0, 0, 0);
      }
    }
    // write staged regs -> other buf
    if (it < 15) {
      *(bf16x8*)&Wt[nbuf * 10240 + inner0] = cvt8(Q0, Q1);
      if (tid < 256) *(bf16x8*)&Wt[nbuf * 10240 + inner1] = cvt8(Q2, Q3);
    }
    __syncthreads();
    za0 = zb0; za1 = zb1; zb0 = nz0; zb1 = nz1;
  }

  // ---- combine k-halves in h_raw (disjoint cells per thread) ----
  if (half == 0) {
#pragma unroll
    for (int mt = 0; mt < 5; ++mt)
#pragma unroll
      for (int r = 0; r < 4; ++r)
        h_raw[(mt * 16 + q * 4 + r) * HR_STRIDE + rb] = acc[mt][r];
  }
  __syncthreads();
  if (half == 1) {
#pragma unroll
    for (int mt = 0; mt < 5; ++mt)
#pragma unroll
      for (int r = 0; r < 4; ++r)
        h_raw[(mt * 16 + q * 4 + r) * HR_STRIDE + rb] += acc[mt][r];
  }
  __syncthreads();

  // ---- BN stats: wave w handles groups w*5 .. w*5+4 ----
#pragma unroll
  for (int s = 0; s < 5; ++s) {
    const int g = w * 5 + s;
    const float2 a = *(const float2*)&h_raw[g * HR_STRIDE + lane * 2];
    float sm = a.x + a.y;
    float sq = a.x * a.x + a.y * a.y;
#pragma unroll
    for (int m = 1; m < 64; m <<= 1) {
      sm += __shfl_xor(sm, m);
      sq += __shfl_xor(sq, m);
    }
    if (lane == 0) {
      float mean = sm * (1.f / 128.f);
      float var  = sq * (1.f / 128.f) - mean * mean;
      var = (var < 0.f) ? 0.f : var;
      float inv   = __builtin_amdgcn_rsqf(var + EPSV);
      float scale = inv * gammap[g0 + g];
      scale_s[g] = scale;
      shift_s[g] = betap[g0 + g] - mean * scale;
    }
  }
  __syncthreads();

  // ---- expansion: 800 threads = 2 batch rows x 400 float4 columns.
  // A wave's store covers 1 KB of contiguous output. ----
  if (tid < 800) {
    const int col4 = tid % 400;          // float4 col in 6400-B window row
    const int r0   = tid / 400;          // 0..1
    const int gl   = col4 / 5;           // local group
    const float4 w4  = cw_s[col4];
    const float  cbv = cb_s[gl];
    const float  scl = scale_s[gl];
    const float  sft = shift_s[gl];
    const float* hsrc = &h_raw[gl * HR_STRIDE];
    float* obase = out + (size_t)g0 * KW + (size_t)col4 * 4;
#pragma unroll 2
    for (int jj = 0; jj < 64; ++jj) {
      const int row = jj * 2 + r0;       // batch index 0..127
      float h = hsrc[row];
      h = fmaf(h, scl, sft);
      h = fmaxf(h, h * 0.1f);            // leaky(0.1)
      float y0 = fmaf(h, w4.x, cbv);
      float y1 = fmaf(h, w4.y, cbv);
      float y2 = fmaf(h, w4.z, cbv);
      float y3 = fmaf(h, w4.w, cbv);
      y0 = fmaxf(y0, y0 * 0.1f);
      y1 = fmaxf(y1, y1 * 0.1f);
      y2 = fmaxf(y2, y2 * 0.1f);
      y3 = fmaxf(y3, y3 * 0.1f);
      float4 ov;
      ov.x = __builtin_amdgcn_rcpf(1.f + exp2f(y0 * -1.44269504f));
      ov.y = __builtin_amdgcn_rcpf(1.f + exp2f(y1 * -1.44269504f));
      ov.z = __builtin_amdgcn_rcpf(1.f + exp2f(y2 * -1.44269504f));
      ov.w = __builtin_amdgcn_rcpf(1.f + exp2f(y3 * -1.44269504f));
      *(float4*)(obase + (size_t)row * OUTW) = ov;
    }
  }
}

// =====================================================================
// Fallback: fused kernel (used only if ws is too small). Reads z directly.
// =====================================================================
#define BKF 64
__global__ __launch_bounds__(256, 2) void fused_decoder_kernel(
    const float* __restrict__ zp, const float* __restrict__ wp,
    const float* __restrict__ gammap, const float* __restrict__ betap,
    const float* __restrict__ convwp, const float* __restrict__ convbp,
    float* __restrict__ out) {
  const int tid = threadIdx.x;
  const int g0  = blockIdx.x * 32;

  __shared__ ushort As[BATCH * BKF];
  __shared__ ushort Bs[32 * BKF];
  __shared__ float statS[2][2][16];
  __shared__ float statQ[2][2][16];

  const int lane = tid & 63;
  const int w    = tid >> 6;
  const int wm   = w & 1;
  const int wn   = w >> 1;
  const int q    = lane >> 4;
  const int cl   = lane & 15;

  f32x4 acc[4];
  const f32x4 vzero = {0.f, 0.f, 0.f, 0.f};
#pragma unroll
  for (int i = 0; i < 4; ++i) acc[i] = vzero;

  for (int it = 0; it < 32; ++it) {
    const int k0 = it * BKF;
    __syncthreads();
#pragma unroll
    for (int i = 0; i < 4; ++i) {
      int c = i * 256 + tid;
      int r = c >> 3, sc = c & 7;
      int gk = k0 + sc * 8;
      int4 v = make_int4(0, 0, 0, 0);
      if (gk < LAT) v = pack8(zp + (size_t)r * LAT + gk);
      *(int4*)&As[r * BKF + ((sc ^ (r & 7)) << 3)] = v;
    }
    {
      int r = tid >> 3, sc = tid & 7;
      int g  = g0 + r;
      int gk = k0 + sc * 8;
      int4 v = make_int4(0, 0, 0, 0);
      if (gk < LAT && g < NG) v = pack8(wp + (size_t)g * LAT + gk);
      *(int4*)&Bs[r * BKF + ((sc ^ (r & 7)) << 3)] = v;
    }
    __syncthreads();
#pragma unroll
    for (int kk = 0; kk < 2; ++kk) {
      int sc = kk * 4 + q;
      bf16x8 af[4], bfr;
#pragma unroll
      for (int mt = 0; mt < 4; ++mt) {
        int ra = wm * 64 + mt * 16 + cl;
        af[mt] = *(const bf16x8*)&As[ra * BKF + ((sc ^ (ra & 7)) << 3)];
      }
      {
        int rbx = wn * 16 + cl;
        bfr = *(const bf16x8*)&Bs[rbx * BKF + ((sc ^ (rbx & 7)) << 3)];
      }
#pragma unroll
      for (int mt = 0; mt < 4; ++mt)
        acc[mt] = __builtin_amdgcn_mfma_f32_16x16x32_bf16(af[mt], bfr,
                                                          acc[mt], 0, 0, 0);
    }
  }

  float s = 0.f, ss = 0.f;
#pragma unroll
  for (int mt = 0; mt < 4; ++mt)
#pragma unroll
    for (int r = 0; r < 4; ++r) {
      float v = acc[mt][r];
      s += v; ss += v * v;
    }
  s += __shfl_xor(s, 16); ss += __shfl_xor(ss, 16);
  s += __shfl_xor(s, 32); ss += __shfl_xor(ss, 32);
  if (q == 0) { statS[wm][wn][cl] = s; statQ[wm][wn][cl] = ss; }
  __syncthreads();

  const int gcol = g0 + wn * 16 + cl;
  const int gc   = (gcol < NG) ? gcol : (NG - 1);
  float S = statS[0][wn][cl] + statS[1][wn][cl];
  float Q = statQ[0][wn][cl] + statQ[1][wn][cl];
  float mean = S * (1.f / 128.f);
  float var  = Q * (1.f / 128.f) - mean * mean;
  var = (var < 0.f) ? 0.f : var;
  float inv = __builtin_amdgcn_rsqf(var + EPSV);
  float ga = gammap[gc], be = betap[gc], cb = convbp[gc];
  float wv[KW];
  {
    const float4* pw = (const float4*)(convwp + (size_t)gc * KW);
#pragma unroll
    for (int j = 0; j < 5; ++j) {
      float4 f = pw[j];
      wv[4 * j] = f.x; wv[4 * j + 1] = f.y;
      wv[4 * j + 2] = f.z; wv[4 * j + 3] = f.w;
    }
  }
  float scale = inv * ga;
  float shift = be - mean * scale;
  const bool ok = (gcol < NG);
#pragma unroll
  for (int mt = 0; mt < 4; ++mt) {
#pragma unroll
    for (int r = 0; r < 4; ++r) {
      float h = acc[mt][r] * scale + shift;
      h = fmaxf(h, h * 0.1f);
      int b = wm * 64 + mt * 16 + q * 4 + r;
      float4 ov[5];
#pragma unroll
      for (int j = 0; j < 5; ++j) {
        float y0 = h * wv[4 * j]     + cb;
        float y1 = h * wv[4 * j + 1] + cb;
        float y2 = h * wv[4 * j + 2] + cb;
        float y3 = h * wv[4 * j + 3] + cb;
        y0 = fmaxf(y0, y0 * 0.1f);
        y1 = fmaxf(y1, y1 * 0.1f);
        y2 = fmaxf(y2, y2 * 0.1f);
        y3 = fmaxf(y3, y3 * 0.1f);
        ov[j].x = __builtin_amdgcn_rcpf(1.f + exp2f(y0 * -1.44269504f));
        ov[j].y = __builtin_amdgcn_rcpf(1.f + exp2f(y1 * -1.44269504f));
        ov[j].z = __builtin_amdgcn_rcpf(1.f + exp2f(y2 * -1.44269504f));
        ov[j].w = __builtin_amdgcn_rcpf(1.f + exp2f(y3 * -1.44269504f));
      }
      if (ok) {
        float4* po = (float4*)(out + (size_t)b * OUTW + (size_t)gcol * KW);
#pragma unroll
        for (int j = 0; j < 5; ++j) po[j] = ov[j];
      }
    }
  }
}

extern "C" void kernel_launch(void* const* d_in, const int* in_sizes, int n_in,
                              void* d_out, int out_size, void* d_ws, size_t ws_size,
                              hipStream_t stream) {
  const float* z     = (const float*)d_in[0];
  const float* W     = (const float*)d_in[1];
  // d_in[2] = b_fc: unused — cancels under training-mode batchnorm
  const float* gamma = (const float*)d_in[3];
  const float* beta  = (const float*)d_in[4];
  const float* convw = (const float*)d_in[5];
  const float* convb = (const float*)d_in[6];
  float* out = (float*)d_out;

  const size_t zlin_bytes = (size_t)BATCH * 256 * 16;   // 512 KB

  if (ws_size >= zlin_bytes) {
    int4* zlin = (int4*)d_ws;
    zprep_kernel<<<128, 256, 0, stream>>>(z, zlin);     // 32768 chunks
    fused80_kernel<<<NG / EG, 1024, 0, stream>>>(zlin, W, gamma, beta,
                                                 convw, convb, out);
  } else {
    fused_decoder_kernel<<<(NG + 31) / 32, 256, 0, stream>>>(
        z, W, gamma, beta, convw, convb, out);
  }
}